// Round 19
// baseline (112.598 us; speedup 1.0000x reference)
//
#include <hip/hip_runtime.h>

#define FDIM 128
#define NT 4
#define KDIM (FDIM * (NT + 1))   // 640 virtual-K
#define GBM 32                    // GEMM M-tile == RNODES

#define RSH 5                     // dst >> 5 -> range id
#define RNODES 32                 // dst nodes per range
#define RCAP 768                  // mean 512, sd ~23 -> 11 sigma headroom
#define NBKT 128                  // 32 dst x 4 types per range
#define CHUNK 4096                // edges per bin block (16/thread)

typedef __attribute__((ext_vector_type(8))) _Float16 h8v;
typedef __attribute__((ext_vector_type(4))) float f4v;

__device__ __forceinline__ unsigned short f2h(float f) {
    _Float16 h = (_Float16)f;
    return __builtin_bit_cast(unsigned short, h);
}
__device__ __forceinline__ void gload_lds16(const void* g, void* l) {
    __builtin_amdgcn_global_load_lds(
        (const __attribute__((address_space(1))) unsigned int*)g,
        (__attribute__((address_space(3))) unsigned int*)l, 16, 0, 0);
}

// ---------------- fused prep: bin + x->f16 + weight mix (r13 verbatim) ---
__global__ __launch_bounds__(256) void k_prep(
    const float* __restrict__ x, const int* __restrict__ ei,
    const int* __restrict__ et, const float* __restrict__ Wself,
    const float* __restrict__ Wneigh, const float* __restrict__ bvec,
    unsigned short* __restrict__ xh, unsigned short* __restrict__ WmixT,
    float* __restrict__ bmean, int* __restrict__ cur,
    unsigned int* __restrict__ bin, int N, int E, int NR, int nbBin, int nbX) {
    __shared__ int lcnt[2048];
    __shared__ int lpos[2048];
    const int bid = blockIdx.x;
    const int tid = threadIdx.x;

    if (bid < nbBin) {
        const int e0 = bid * CHUNK;
        for (int b = tid; b < NR; b += 256) lcnt[b] = 0;
        __syncthreads();
        int rs[16];
        unsigned int recs[16];
#pragma unroll
        for (int i = 0; i < 16; ++i) {
            int e = e0 + i * 256 + tid;
            if (e < E) {
                int src = ei[e];
                int dst = ei[E + e];
                int t = et[e];
                rs[i] = dst >> RSH;
                recs[i] = (unsigned int)src |
                          ((unsigned int)(dst & (RNODES - 1)) << 16) |
                          ((unsigned int)t << 21);
                atomicAdd(&lcnt[rs[i]], 1);
            } else { rs[i] = -1; recs[i] = 0; }
        }
        __syncthreads();
        for (int b = tid; b < NR; b += 256) {
            int c = lcnt[b];
            lpos[b] = (c > 0) ? atomicAdd(&cur[b * 16], c) : 0;
        }
        __syncthreads();
#pragma unroll
        for (int i = 0; i < 16; ++i) {
            if (rs[i] >= 0) {
                int p = atomicAdd(&lpos[rs[i]], 1);
                if (p < RCAP) bin[(size_t)rs[i] * RCAP + p] = recs[i];
            }
        }
    } else if (bid < nbBin + nbX) {
        int i = (bid - nbBin) * 256 + tid;          // 8 f32 -> 8 f16 each
        int n8 = N * FDIM / 8;
        if (i < n8) {
            float4 v0 = reinterpret_cast<const float4*>(x)[i * 2];
            float4 v1 = reinterpret_cast<const float4*>(x)[i * 2 + 1];
            ushort4 o0, o1;
            o0.x = f2h(v0.x); o0.y = f2h(v0.y); o0.z = f2h(v0.z); o0.w = f2h(v0.w);
            o1.x = f2h(v1.x); o1.y = f2h(v1.y); o1.z = f2h(v1.z); o1.w = f2h(v1.w);
            reinterpret_cast<ushort4*>(xh)[i * 2] = o0;
            reinterpret_cast<ushort4*>(xh)[i * 2 + 1] = o1;
        }
    } else {
        int i = (bid - nbBin - nbX) * 256 + tid;
        if (i < KDIM * FDIM) {
            int k = i / FDIM, j = i % FDIM;
            float v;
            if (k < FDIM) {
                v = 0.25f * (Wself[(size_t)(0 * FDIM + k) * FDIM + j] +
                             Wself[(size_t)(1 * FDIM + k) * FDIM + j] +
                             Wself[(size_t)(2 * FDIM + k) * FDIM + j] +
                             Wself[(size_t)(3 * FDIM + k) * FDIM + j]);
            } else {
                int t = (k - FDIM) >> 7;
                int kk = (k - FDIM) & (FDIM - 1);
                v = 0.25f * Wneigh[((size_t)t * FDIM + kk) * FDIM + j];
            }
            WmixT[(size_t)j * KDIM + k] = f2h(v);
            if (i < FDIM)
                bmean[i] = 0.25f * (bvec[i] + bvec[FDIM + i] +
                                    bvec[2 * FDIM + i] + bvec[3 * FDIM + i]);
        }
    }
}

// ---------------- fused: sort + batched REGISTER gather + MFMA GEMM ------
// r13 resource shape (18944 B LDS) but the gather of ALL 4 types runs in
// ONE barrier-free window into res[8] registers (static indexing via full
// unroll). Phase 3b replays r13's staged K-steps per type.
__global__ __launch_bounds__(256) void k_fused(
    const unsigned short* __restrict__ xh, const int* __restrict__ cur,
    const unsigned int* __restrict__ bin, const unsigned short* __restrict__ WmixT,
    const float* __restrict__ bmean, float* __restrict__ out, int N) {
    __shared__ __align__(16) char smem[18944];
    unsigned int* recs   = (unsigned int*)smem;                  // phase 1
    int* cur2            = (int*)(smem + 3584);                  // phase 1
    unsigned short* As   = (unsigned short*)smem;                // phase 2
    unsigned short* magg = (unsigned short*)smem;                // phase 3
    unsigned short* srcs = (unsigned short*)(smem + 8192);
    int* cnts            = (int*)(smem + 9728);
    int* boff            = (int*)(smem + 10240);
    unsigned short* Bs   = (unsigned short*)(smem + 10752);

    const int r = blockIdx.x;
    const int tid = threadIdx.x;

    // ---- phase 1: LDS counting-sort ----
    int K = cur[r * 16];
    if (K > RCAP) K = RCAP;
    for (int i = tid; i < K; i += 256) recs[i] = bin[(size_t)r * RCAP + i];
    if (tid < NBKT) cnts[tid] = 0;
    __syncthreads();
    for (int i = tid; i < K; i += 256) {
        unsigned int rec = recs[i];
        int b = ((rec >> 21) << 5) | ((rec >> 16) & 31);
        atomicAdd(&cnts[b], 1);
    }
    __syncthreads();
    if (tid < 64) {   // wave-0 shfl scan of 128 buckets
        int c0 = cnts[2 * tid], c1 = cnts[2 * tid + 1];
        int tot = c0 + c1;
        int xs = tot;
        for (int off = 1; off < 64; off <<= 1) {
            int y = __shfl_up(xs, off, 64);
            if (tid >= off) xs += y;
        }
        int excl = xs - tot;
        boff[2 * tid] = excl;
        boff[2 * tid + 1] = excl + c0;
        cur2[2 * tid] = excl;
        cur2[2 * tid + 1] = excl + c0;
    }
    __syncthreads();
    for (int i = tid; i < K; i += 256) {
        unsigned int rec = recs[i];
        int b = ((rec >> 21) << 5) | ((rec >> 16) & 31);
        int p = atomicAdd(&cur2[b], 1);
        srcs[p] = (unsigned short)(rec & 0xffffu);
    }

    const int wid = tid >> 6, lane = tid & 63;
    const int wr = wid >> 1, wc = wid & 1;
    const int n0 = r * GBM;
    const int r16 = lane & 15, kg = lane >> 4;
    const int g = tid >> 4, ln = tid & 15;

    f4v acc[4];
#pragma unroll
    for (int n = 0; n < 4; ++n) acc[n] = (f4v){0.f, 0.f, 0.f, 0.f};
    __syncthreads();   // recs/cur2 dead; As region free

    // ---- phase 2: segment 0 (self term), r13 staged ----
#pragma unroll 1
    for (int ks = 0; ks < 4; ++ks) {
        int k0 = ks * 32;
        if (wid < 2) {   // A tile 32x32: 2 waves, 16 rows each
            int row = tid >> 2, c = tid & 3;
            int cs = c ^ ((row >> 1) & 3);
            int rg = n0 + row; if (rg >= N) rg = N - 1;
            gload_lds16(xh + (size_t)rg * FDIM + k0 + cs * 8, &As[wid * 512]);
        }
#pragma unroll
        for (int p = 0; p < 2; ++p) {
            int ck = p * 256 + tid;
            int col = ck >> 2, c = ck & 3;
            int cs = c ^ ((col >> 1) & 3);
            gload_lds16(WmixT + (size_t)col * KDIM + k0 + cs * 8,
                        &Bs[(p * 4 + wid) * 512]);
        }
        __syncthreads();
        h8v af, bfr[4];
        {
            int row = wr * 16 + r16;
            af = *reinterpret_cast<const h8v*>(
                &As[row * 32 + ((kg ^ ((row >> 1) & 3)) << 3)]);
        }
#pragma unroll
        for (int n = 0; n < 4; ++n) {
            int col = wc * 64 + n * 16 + r16;
            bfr[n] = *reinterpret_cast<const h8v*>(
                &Bs[col * 32 + ((kg ^ ((col >> 1) & 3)) << 3)]);
        }
#pragma unroll
        for (int n = 0; n < 4; ++n)
            acc[n] = __builtin_amdgcn_mfma_f32_16x16x32_f16(af, bfr[n], acc[n], 0, 0, 0);
        __syncthreads();
    }

    // ---- phase 3a: batched register gather of ALL 4 types (one window) --
    h8v res[8];
#pragma unroll
    for (int u = 0; u < 8; ++u) {
        const int t = u >> 1, it = u & 1;
        int dl = it * 16 + g;
        int b = (t << 5) | dl;
        int dst = n0 + dl;
        h8v a0 = (h8v)(_Float16)0.f, a1 = (h8v)(_Float16)0.f;
        h8v a2 = (h8v)(_Float16)0.f, a3 = (h8v)(_Float16)0.f;
        float rc = 0.0f;
        if (dst < N) {
            int beg = boff[b], m = cnts[b];
            int i = 0;
            for (; i + 4 <= m; i += 4) {
                int s0 = srcs[beg + i], s1 = srcs[beg + i + 1];
                int s2 = srcs[beg + i + 2], s3 = srcs[beg + i + 3];
                a0 += *reinterpret_cast<const h8v*>(xh + (size_t)s0 * FDIM + ln * 8);
                a1 += *reinterpret_cast<const h8v*>(xh + (size_t)s1 * FDIM + ln * 8);
                a2 += *reinterpret_cast<const h8v*>(xh + (size_t)s2 * FDIM + ln * 8);
                a3 += *reinterpret_cast<const h8v*>(xh + (size_t)s3 * FDIM + ln * 8);
            }
            if (i + 2 <= m) {
                int s0 = srcs[beg + i], s1 = srcs[beg + i + 1];
                a0 += *reinterpret_cast<const h8v*>(xh + (size_t)s0 * FDIM + ln * 8);
                a1 += *reinterpret_cast<const h8v*>(xh + (size_t)s1 * FDIM + ln * 8);
                i += 2;
            }
            if (i < m) {
                int s0 = srcs[beg + i];
                a0 += *reinterpret_cast<const h8v*>(xh + (size_t)s0 * FDIM + ln * 8);
            }
            rc = (m > 0) ? 1.0f / (float)m : 0.0f;
        }
        res[u] = ((a0 + a1) + (a2 + a3)) * (_Float16)rc;
    }

    // ---- phase 3b: per type {magg write from regs -> 4 staged K-steps} --
#pragma unroll
    for (int t = 0; t < 4; ++t) {
#pragma unroll
        for (int it = 0; it < 2; ++it) {
            int dl = it * 16 + g;
            if (n0 + dl < N)
                *reinterpret_cast<h8v*>(
                    &magg[dl * FDIM + ((ln ^ (dl & 15)) << 3)]) = res[t * 2 + it];
        }
        // first ks barrier (below) publishes magg; prior trailing barrier
        // guarantees previous type's magg reads are complete.
#pragma unroll 1
        for (int ks = 0; ks < 4; ++ks) {
            int k0 = FDIM + t * FDIM + ks * 32;
#pragma unroll
            for (int p = 0; p < 2; ++p) {
                int ck = p * 256 + tid;
                int col = ck >> 2, c = ck & 3;
                int cs = c ^ ((col >> 1) & 3);
                gload_lds16(WmixT + (size_t)col * KDIM + k0 + cs * 8,
                            &Bs[(p * 4 + wid) * 512]);
            }
            __syncthreads();
            h8v af, bfr[4];
            {
                int row = wr * 16 + r16;
                af = *reinterpret_cast<const h8v*>(
                    &magg[row * FDIM + (((ks * 4 + kg) ^ (row & 15)) << 3)]);
            }
#pragma unroll
            for (int n = 0; n < 4; ++n) {
                int col = wc * 64 + n * 16 + r16;
                bfr[n] = *reinterpret_cast<const h8v*>(
                    &Bs[col * 32 + ((kg ^ ((col >> 1) & 3)) << 3)]);
            }
#pragma unroll
            for (int n = 0; n < 4; ++n)
                acc[n] = __builtin_amdgcn_mfma_f32_16x16x32_f16(af, bfr[n], acc[n], 0, 0, 0);
            __syncthreads();
        }
    }

    // ---- epilogue: C/D layout col=lane&15, row=(lane>>4)*4+reg ----
    float bm[4];
#pragma unroll
    for (int n = 0; n < 4; ++n) bm[n] = bmean[wc * 64 + n * 16 + r16];
#pragma unroll
    for (int j = 0; j < 4; ++j) {
        int row = n0 + wr * 16 + kg * 4 + j;
        if (row < N) {
            float* o = out + (size_t)row * FDIM;
#pragma unroll
            for (int n = 0; n < 4; ++n)
                o[wc * 64 + n * 16 + r16] = acc[n][j] + bm[n];
        }
    }
}

extern "C" void kernel_launch(void* const* d_in, const int* in_sizes, int n_in,
                              void* d_out, int out_size, void* d_ws, size_t ws_size,
                              hipStream_t stream) {
    const float* x      = (const float*)d_in[0];
    const int*   ei     = (const int*)d_in[1];
    const int*   et     = (const int*)d_in[2];
    const float* Wself  = (const float*)d_in[3];
    const float* Wneigh = (const float*)d_in[4];
    const float* b      = (const float*)d_in[5];
    float* out = (float*)d_out;

    const int N = in_sizes[0] / FDIM;
    const int E = in_sizes[2];
    const int NR = (N + RNODES - 1) >> RSH;    // 1563 ranges == GEMM tiles

    char* ws = (char*)d_ws;
    unsigned short* xh    = (unsigned short*)ws;                 // N*FDIM f16
    unsigned short* WmixT = xh + (size_t)N * FDIM;               // 128*640 f16
    float* bmean = (float*)(WmixT + (size_t)FDIM * KDIM);        // FDIM f32
    int* cur     = (int*)(bmean + FDIM);                         // NR*16
    unsigned int* bin = (unsigned int*)(cur + (size_t)NR * 16);  // NR*RCAP u32

    hipMemsetAsync(cur, 0, (size_t)NR * 16 * sizeof(int), stream);

    const int nbBin = (E + CHUNK - 1) / CHUNK;                   // 196
    const int nbX   = (N * FDIM / 8 + 255) / 256;                // 3125
    const int nbM   = (KDIM * FDIM + 255) / 256;                 // 320

    k_prep<<<nbBin + nbX + nbM, 256, 0, stream>>>(
        x, ei, et, Wself, Wneigh, b, xh, WmixT, bmean, cur, bin,
        N, E, NR, nbBin, nbX);

    k_fused<<<NR, 256, 0, stream>>>(xh, cur, bin, WmixT, bmean, out, N);
}

// Round 20
// 87.438 us; speedup vs baseline: 1.2877x; 1.2877x over previous
//
#include <hip/hip_runtime.h>

#define FDIM 128
#define NT 4
#define KDIM (FDIM * (NT + 1))   // 640 virtual-K
#define GBM 32                    // GEMM M-tile == RNODES

#define RSH 5                     // dst >> 5 -> range id
#define RNODES 32                 // dst nodes per range
#define RCAP 768                  // mean 512, sd ~23 -> 11 sigma headroom
#define NBKT 128                  // 32 dst x 4 types per range
#define CHUNK 4096                // edges per bin block (16/thread)

typedef __attribute__((ext_vector_type(8))) _Float16 h8v;
typedef __attribute__((ext_vector_type(4))) float f4v;

__device__ __forceinline__ unsigned short f2h(float f) {
    _Float16 h = (_Float16)f;
    return __builtin_bit_cast(unsigned short, h);
}
__device__ __forceinline__ void gload_lds16(const void* g, void* l) {
    __builtin_amdgcn_global_load_lds(
        (const __attribute__((address_space(1))) unsigned int*)g,
        (__attribute__((address_space(3))) unsigned int*)l, 16, 0, 0);
}

// ---------------- fused prep: bin + x->f16 + weight mix ------------------
// blocks [0,nbBin): multi-split edge binning; [nbBin,nbBin+nbX): x2h;
// [nbBin+nbX, +nbM): weight mix.  rec = src | dl<<16 | t<<21
__global__ __launch_bounds__(256) void k_prep(
    const float* __restrict__ x, const int* __restrict__ ei,
    const int* __restrict__ et, const float* __restrict__ Wself,
    const float* __restrict__ Wneigh, const float* __restrict__ bvec,
    unsigned short* __restrict__ xh, unsigned short* __restrict__ WmixT,
    float* __restrict__ bmean, int* __restrict__ cur,
    unsigned int* __restrict__ bin, int N, int E, int NR, int nbBin, int nbX) {
    __shared__ int lcnt[2048];
    __shared__ int lpos[2048];
    const int bid = blockIdx.x;
    const int tid = threadIdx.x;

    if (bid < nbBin) {
        const int e0 = bid * CHUNK;
        for (int b = tid; b < NR; b += 256) lcnt[b] = 0;
        __syncthreads();
        int rs[16];
        unsigned int recs[16];
#pragma unroll
        for (int i = 0; i < 16; ++i) {
            int e = e0 + i * 256 + tid;
            if (e < E) {
                int src = ei[e];
                int dst = ei[E + e];
                int t = et[e];
                rs[i] = dst >> RSH;
                recs[i] = (unsigned int)src |
                          ((unsigned int)(dst & (RNODES - 1)) << 16) |
                          ((unsigned int)t << 21);
                atomicAdd(&lcnt[rs[i]], 1);
            } else { rs[i] = -1; recs[i] = 0; }
        }
        __syncthreads();
        for (int b = tid; b < NR; b += 256) {
            int c = lcnt[b];
            lpos[b] = (c > 0) ? atomicAdd(&cur[b * 16], c) : 0;
        }
        __syncthreads();
#pragma unroll
        for (int i = 0; i < 16; ++i) {
            if (rs[i] >= 0) {
                int p = atomicAdd(&lpos[rs[i]], 1);
                if (p < RCAP) bin[(size_t)rs[i] * RCAP + p] = recs[i];
            }
        }
    } else if (bid < nbBin + nbX) {
        int i = (bid - nbBin) * 256 + tid;          // 8 f32 -> 8 f16 each
        int n8 = N * FDIM / 8;
        if (i < n8) {
            float4 v0 = reinterpret_cast<const float4*>(x)[i * 2];
            float4 v1 = reinterpret_cast<const float4*>(x)[i * 2 + 1];
            ushort4 o0, o1;
            o0.x = f2h(v0.x); o0.y = f2h(v0.y); o0.z = f2h(v0.z); o0.w = f2h(v0.w);
            o1.x = f2h(v1.x); o1.y = f2h(v1.y); o1.z = f2h(v1.z); o1.w = f2h(v1.w);
            reinterpret_cast<ushort4*>(xh)[i * 2] = o0;
            reinterpret_cast<ushort4*>(xh)[i * 2 + 1] = o1;
        }
    } else {
        int i = (bid - nbBin - nbX) * 256 + tid;
        if (i < KDIM * FDIM) {
            int k = i / FDIM, j = i % FDIM;
            float v;
            if (k < FDIM) {
                v = 0.25f * (Wself[(size_t)(0 * FDIM + k) * FDIM + j] +
                             Wself[(size_t)(1 * FDIM + k) * FDIM + j] +
                             Wself[(size_t)(2 * FDIM + k) * FDIM + j] +
                             Wself[(size_t)(3 * FDIM + k) * FDIM + j]);
            } else {
                int t = (k - FDIM) >> 7;
                int kk = (k - FDIM) & (FDIM - 1);
                v = 0.25f * Wneigh[((size_t)t * FDIM + kk) * FDIM + j];
            }
            WmixT[(size_t)j * KDIM + k] = f2h(v);
            if (i < FDIM)
                bmean[i] = 0.25f * (bvec[i] + bvec[FDIM + i] +
                                    bvec[2 * FDIM + i] + bvec[3 * FDIM + i]);
        }
    }
}

// ---------------- fused: sort + per-type aggregate + MFMA GEMM -----------
// Round-11 structure (18944 B LDS, ~8 blocks/CU) with the Hillis-Steele
// scan replaced by a wave-0 shfl scan (13 fewer barriers).
__global__ __launch_bounds__(256) void k_fused(
    const unsigned short* __restrict__ xh, const int* __restrict__ cur,
    const unsigned int* __restrict__ bin, const unsigned short* __restrict__ WmixT,
    const float* __restrict__ bmean, float* __restrict__ out, int N) {
    __shared__ __align__(16) char smem[18944];
    unsigned int* recs   = (unsigned int*)smem;                  // phase 1
    int* cur2            = (int*)(smem + 3584);                  // phase 1
    unsigned short* As   = (unsigned short*)smem;                // phase 2
    unsigned short* magg = (unsigned short*)smem;                // phase 3
    unsigned short* srcs = (unsigned short*)(smem + 8192);
    int* cnts            = (int*)(smem + 9728);
    int* boff            = (int*)(smem + 10240);
    unsigned short* Bs   = (unsigned short*)(smem + 10752);

    const int r = blockIdx.x;
    const int tid = threadIdx.x;

    // ---- phase 1: LDS counting-sort of this range's records ----
    int K = cur[r * 16];
    if (K > RCAP) K = RCAP;
    for (int i = tid; i < K; i += 256) recs[i] = bin[(size_t)r * RCAP + i];
    if (tid < NBKT) cnts[tid] = 0;
    __syncthreads();
    for (int i = tid; i < K; i += 256) {
        unsigned int rec = recs[i];
        int b = ((rec >> 21) << 5) | ((rec >> 16) & 31);
        atomicAdd(&cnts[b], 1);
    }
    __syncthreads();
    if (tid < 64) {   // wave-0 shfl scan of 128 buckets, no barriers
        int c0 = cnts[2 * tid], c1 = cnts[2 * tid + 1];
        int tot = c0 + c1;
        int xs = tot;
        for (int off = 1; off < 64; off <<= 1) {
            int y = __shfl_up(xs, off, 64);
            if (tid >= off) xs += y;
        }
        int excl = xs - tot;
        boff[2 * tid] = excl;
        boff[2 * tid + 1] = excl + c0;
        cur2[2 * tid] = excl;
        cur2[2 * tid + 1] = excl + c0;
    }
    __syncthreads();
    for (int i = tid; i < K; i += 256) {
        unsigned int rec = recs[i];
        int b = ((rec >> 21) << 5) | ((rec >> 16) & 31);
        int p = atomicAdd(&cur2[b], 1);
        srcs[p] = (unsigned short)(rec & 0xffffu);
    }

    // ---- GEMM setup: 4 waves, each 16 rows x 64 cols of the 32x128 tile --
    const int wid = tid >> 6, lane = tid & 63;
    const int wr = wid >> 1, wc = wid & 1;
    const int n0 = r * GBM;
    const int r16 = lane & 15, kg = lane >> 4;
    const int g = tid >> 4, ln = tid & 15;

    f4v acc[4];
#pragma unroll
    for (int n = 0; n < 4; ++n) acc[n] = (f4v){0.f, 0.f, 0.f, 0.f};
    __syncthreads();   // recs/cur2 dead; As region live next

    // ---- phase 2: segment 0 (self term) from xh ----
#pragma unroll 1
    for (int ks = 0; ks < 4; ++ks) {
        int k0 = ks * 32;
        if (wid < 2) {   // A tile 32x32: 2 waves, 16 rows each
            int row = tid >> 2, c = tid & 3;
            int cs = c ^ ((row >> 1) & 3);
            int rg = n0 + row; if (rg >= N) rg = N - 1;
            gload_lds16(xh + (size_t)rg * FDIM + k0 + cs * 8, &As[wid * 512]);
        }
#pragma unroll
        for (int p = 0; p < 2; ++p) {
            int ck = p * 256 + tid;
            int col = ck >> 2, c = ck & 3;
            int cs = c ^ ((col >> 1) & 3);
            gload_lds16(WmixT + (size_t)col * KDIM + k0 + cs * 8,
                        &Bs[(p * 4 + wid) * 512]);
        }
        __syncthreads();
        h8v af, bfr[4];
        {
            int row = wr * 16 + r16;
            af = *reinterpret_cast<const h8v*>(
                &As[row * 32 + ((kg ^ ((row >> 1) & 3)) << 3)]);
        }
#pragma unroll
        for (int n = 0; n < 4; ++n) {
            int col = wc * 64 + n * 16 + r16;
            bfr[n] = *reinterpret_cast<const h8v*>(
                &Bs[col * 32 + ((kg ^ ((col >> 1) & 3)) << 3)]);
        }
#pragma unroll
        for (int n = 0; n < 4; ++n)
            acc[n] = __builtin_amdgcn_mfma_f32_16x16x32_f16(af, bfr[n], acc[n], 0, 0, 0);
        __syncthreads();
    }

    // ---- phase 3: per-type {aggregate -> LDS magg -> 4 K-steps} ----
#pragma unroll 1
    for (int t = 0; t < 4; ++t) {
        // aggregate 32 buckets of type t into magg (swizzled granules)
#pragma unroll 1
        for (int it = 0; it < 2; ++it) {
            int dl = it * 16 + g;
            int b = (t << 5) | dl;
            int dst = n0 + dl;
            if (dst < N) {
                int beg = boff[b], m = cnts[b];
                h8v a0 = (h8v)(_Float16)0.f, a1 = (h8v)(_Float16)0.f;
                h8v a2 = (h8v)(_Float16)0.f, a3 = (h8v)(_Float16)0.f;
                int i = 0;
                for (; i + 4 <= m; i += 4) {
                    int s0 = srcs[beg + i], s1 = srcs[beg + i + 1];
                    int s2 = srcs[beg + i + 2], s3 = srcs[beg + i + 3];
                    a0 += *reinterpret_cast<const h8v*>(xh + (size_t)s0 * FDIM + ln * 8);
                    a1 += *reinterpret_cast<const h8v*>(xh + (size_t)s1 * FDIM + ln * 8);
                    a2 += *reinterpret_cast<const h8v*>(xh + (size_t)s2 * FDIM + ln * 8);
                    a3 += *reinterpret_cast<const h8v*>(xh + (size_t)s3 * FDIM + ln * 8);
                }
                if (i + 2 <= m) {
                    int s0 = srcs[beg + i], s1 = srcs[beg + i + 1];
                    a0 += *reinterpret_cast<const h8v*>(xh + (size_t)s0 * FDIM + ln * 8);
                    a1 += *reinterpret_cast<const h8v*>(xh + (size_t)s1 * FDIM + ln * 8);
                    i += 2;
                }
                if (i < m) {
                    int s0 = srcs[beg + i];
                    a0 += *reinterpret_cast<const h8v*>(xh + (size_t)s0 * FDIM + ln * 8);
                }
                float rc = (m > 0) ? 1.0f / (float)m : 0.0f;
                h8v o = ((a0 + a1) + (a2 + a3)) * (_Float16)rc;
                *reinterpret_cast<h8v*>(&magg[dl * FDIM + ((ln ^ (dl & 15)) << 3)]) = o;
            }
        }
        __syncthreads();

#pragma unroll 1
        for (int ks = 0; ks < 4; ++ks) {
            int k0 = FDIM + t * FDIM + ks * 32;
#pragma unroll
            for (int p = 0; p < 2; ++p) {
                int ck = p * 256 + tid;
                int col = ck >> 2, c = ck & 3;
                int cs = c ^ ((col >> 1) & 3);
                gload_lds16(WmixT + (size_t)col * KDIM + k0 + cs * 8,
                            &Bs[(p * 4 + wid) * 512]);
            }
            __syncthreads();
            h8v af, bfr[4];
            {
                int row = wr * 16 + r16;
                af = *reinterpret_cast<const h8v*>(
                    &magg[row * FDIM + (((ks * 4 + kg) ^ (row & 15)) << 3)]);
            }
#pragma unroll
            for (int n = 0; n < 4; ++n) {
                int col = wc * 64 + n * 16 + r16;
                bfr[n] = *reinterpret_cast<const h8v*>(
                    &Bs[col * 32 + ((kg ^ ((col >> 1) & 3)) << 3)]);
            }
#pragma unroll
            for (int n = 0; n < 4; ++n)
                acc[n] = __builtin_amdgcn_mfma_f32_16x16x32_f16(af, bfr[n], acc[n], 0, 0, 0);
            __syncthreads();
        }
    }

    // ---- epilogue: C/D layout col=lane&15, row=(lane>>4)*4+reg ----
    float bm[4];
#pragma unroll
    for (int n = 0; n < 4; ++n) bm[n] = bmean[wc * 64 + n * 16 + r16];
#pragma unroll
    for (int j = 0; j < 4; ++j) {
        int row = n0 + wr * 16 + kg * 4 + j;
        if (row < N) {
            float* o = out + (size_t)row * FDIM;
#pragma unroll
            for (int n = 0; n < 4; ++n)
                o[wc * 64 + n * 16 + r16] = acc[n][j] + bm[n];
        }
    }
}

extern "C" void kernel_launch(void* const* d_in, const int* in_sizes, int n_in,
                              void* d_out, int out_size, void* d_ws, size_t ws_size,
                              hipStream_t stream) {
    const float* x      = (const float*)d_in[0];
    const int*   ei     = (const int*)d_in[1];
    const int*   et     = (const int*)d_in[2];
    const float* Wself  = (const float*)d_in[3];
    const float* Wneigh = (const float*)d_in[4];
    const float* b      = (const float*)d_in[5];
    float* out = (float*)d_out;

    const int N = in_sizes[0] / FDIM;
    const int E = in_sizes[2];
    const int NR = (N + RNODES - 1) >> RSH;    // 1563 ranges == GEMM tiles

    char* ws = (char*)d_ws;
    unsigned short* xh    = (unsigned short*)ws;                 // N*FDIM f16
    unsigned short* WmixT = xh + (size_t)N * FDIM;               // 128*640 f16
    float* bmean = (float*)(WmixT + (size_t)FDIM * KDIM);        // FDIM f32
    int* cur     = (int*)(bmean + FDIM);                         // NR*16
    unsigned int* bin = (unsigned int*)(cur + (size_t)NR * 16);  // NR*RCAP u32

    hipMemsetAsync(cur, 0, (size_t)NR * 16 * sizeof(int), stream);

    const int nbBin = (E + CHUNK - 1) / CHUNK;                   // 196
    const int nbX   = (N * FDIM / 8 + 255) / 256;                // 3125
    const int nbM   = (KDIM * FDIM + 255) / 256;                 // 320

    k_prep<<<nbBin + nbX + nbM, 256, 0, stream>>>(
        x, ei, et, Wself, Wneigh, b, xh, WmixT, bmean, cur, bin,
        N, E, NR, nbBin, nbX);

    k_fused<<<NR, 256, 0, stream>>>(xh, cur, bin, WmixT, bmean, out, N);
}